// Round 2
// baseline (250.254 us; speedup 1.0000x reference)
//
#include <hip/hip_runtime.h>
#include <stdint.h>

#define Bdim 64
#define Ndim 16
#define Idim 2048
#define Ddim 32
#define Kdim 32
#define EPSV 1e-7f

typedef __attribute__((ext_vector_type(8))) short short8v;
typedef __attribute__((ext_vector_type(4))) float f32x4;

static __device__ __forceinline__ unsigned cvt_pk_bf16(float lo, float hi) {
    unsigned r;
    asm("v_cvt_pk_bf16_f32 %0, %1, %2" : "=v"(r) : "v"(lo), "v"(hi));
    return r;
}
static __device__ __forceinline__ float bf2f(unsigned us) {
    return __uint_as_float(us << 16);
}

// -------- Pass 1: u_hat[b,i,n,d] (bf16) = W[n,i,:,:] @ x[b,i,:]; s0_raw[b,n,d] += sum_i u_hat
// grid = (N, I/64); block = 64*(Bc/16) threads; wave w handles b-columns [w*16, w*16+16)
__global__ __launch_bounds__(256) void pass1_kernel(
    const float* __restrict__ W, const float* __restrict__ x,
    unsigned short* __restrict__ uhat, float* __restrict__ s0, int bbase)
{
    const int n  = blockIdx.x;
    const int i0 = blockIdx.y * 64;
    const int w  = threadIdx.x >> 6;
    const int l  = threadIdx.x & 63;
    const int bcol  = (w << 4) + (l & 15);   // chunk-local b (MFMA N-col)
    const int bglob = bbase + bcol;          // global b
    const int krow  = l >> 4;                // k-chunk 0..3 (8 k's each)

    f32x4 acc[2];
    acc[0] = (f32x4){0.f, 0.f, 0.f, 0.f};
    acc[1] = (f32x4){0.f, 0.f, 0.f, 0.f};
    const f32x4 zero = {0.f, 0.f, 0.f, 0.f};

    for (int ii = 0; ii < 64; ++ii) {
        const int i = i0 + ii;
        // B fragment: x[bglob][i][krow*8 .. +8]  (B-layout: col=l&15, k=(l>>4)*8+e)
        const float* xp = x + ((size_t)bglob * Idim + i) * Kdim + (krow << 3);
        float4 xa = ((const float4*)xp)[0];
        float4 xb = ((const float4*)xp)[1];
        union { short8v v; unsigned u[4]; } bfrag;
        bfrag.u[0] = cvt_pk_bf16(xa.x, xa.y);
        bfrag.u[1] = cvt_pk_bf16(xa.z, xa.w);
        bfrag.u[2] = cvt_pk_bf16(xb.x, xb.y);
        bfrag.u[3] = cvt_pk_bf16(xb.z, xb.w);

        const float* wbase = W + ((size_t)n * Idim + i) * Ddim * Kdim + (krow << 3);
        #pragma unroll
        for (int mt = 0; mt < 2; ++mt) {
            // A fragment: W[n][i][d = mt*16 + (l&15)][krow*8 .. +8]  (A-layout: row=l&15)
            const int d0 = (mt << 4) + (l & 15);
            const float* wp = wbase + (size_t)d0 * Kdim;
            float4 wa = ((const float4*)wp)[0];
            float4 wb = ((const float4*)wp)[1];
            union { short8v v; unsigned u[4]; } afrag;
            afrag.u[0] = cvt_pk_bf16(wa.x, wa.y);
            afrag.u[1] = cvt_pk_bf16(wa.z, wa.w);
            afrag.u[2] = cvt_pk_bf16(wb.x, wb.y);
            afrag.u[3] = cvt_pk_bf16(wb.z, wb.w);

            f32x4 c = __builtin_amdgcn_mfma_f32_16x16x32_bf16(afrag.v, bfrag.v, zero, 0, 0, 0);
            // C/D layout: col(b) = l&15, row(d within tile) = (l>>4)*4 + reg
            const int dst = (mt << 4) + (krow << 2);
            size_t uoff = (((size_t)bcol * Idim + i) * Ndim + n) * Ddim + dst;
            uint2 pk;
            pk.x = cvt_pk_bf16(c[0], c[1]);
            pk.y = cvt_pk_bf16(c[2], c[3]);
            *(uint2*)(uhat + uoff) = pk;   // 8B store, 32B sector fully covered by 4 lanes
            acc[mt] += c;
        }
    }
    // s0_raw[bglob][n][d] += acc  (true s0 = raw/16, folded into squash scale)
    #pragma unroll
    for (int mt = 0; mt < 2; ++mt) {
        const int dbase = (mt << 4) + (krow << 2);
        float* sp = s0 + ((size_t)bglob * Ndim + n) * Ddim + dbase;
        #pragma unroll
        for (int r = 0; r < 4; ++r) atomicAdd(sp + r, acc[mt][r]);
    }
}

// -------- Routing pass: per (b,i): a[n]=u.v ; logits=(b_old)+a ; c=softmax_n ; s += c*u
// grid = (Bc, I/128); block = 256 (4 waves, wave handles i = it*128 + w + 4*t)
// lane mapping: g = l>>2 -> n (16 groups), q = l&3 -> d-octet
template<int FIRST>
__global__ __launch_bounds__(256) void route_kernel(
    const unsigned short* __restrict__ uhat, const float* __restrict__ vin,
    float* __restrict__ bbuf, float* __restrict__ sout, int bbase)
{
    const int bc = blockIdx.x;
    const int it = blockIdx.y;
    const int w = threadIdx.x >> 6;
    const int l = threadIdx.x & 63;
    const int g = l >> 2, q = l & 3;
    const int bglob = bbase + bc;

    // preload v[bglob][g][q*8 .. +8] once (constant over i)
    const float* vp = vin + ((size_t)bglob * Ndim + g) * Ddim + (q << 3);
    float vreg[8];
    *(float4*)&vreg[0] = ((const float4*)vp)[0];
    *(float4*)&vreg[4] = ((const float4*)vp)[1];

    float sacc[8];
    #pragma unroll
    for (int j = 0; j < 8; ++j) sacc[j] = 0.f;

    for (int ii = w; ii < 128; ii += 4) {
        const int i = (it << 7) + ii;
        // u_hat[bc][i][g][q*8 .. +8]  == flat (bc*I+i)*512 + 8*l  -> wave reads 1KB contiguous
        const unsigned short* up = uhat + ((size_t)bc * Idim + i) * (Ndim * Ddim) + (l << 3);
        uint4 uraw = *(const uint4*)up;
        float u[8];
        u[0] = bf2f(uraw.x & 0xffffu); u[1] = bf2f(uraw.x >> 16);
        u[2] = bf2f(uraw.y & 0xffffu); u[3] = bf2f(uraw.y >> 16);
        u[4] = bf2f(uraw.z & 0xffffu); u[5] = bf2f(uraw.z >> 16);
        u[6] = bf2f(uraw.w & 0xffffu); u[7] = bf2f(uraw.w >> 16);

        float p = 0.f;
        #pragma unroll
        for (int j = 0; j < 8; ++j) p = fmaf(u[j], vreg[j], p);
        p += __shfl_xor(p, 1);
        p += __shfl_xor(p, 2);          // a[n=g] in all 4 lanes of group

        float logit = p;
        if (FIRST) {
            if (q == 0) bbuf[((size_t)bc * Idim + i) * Ndim + g] = p;  // b1 = a0
        } else {
            logit += bbuf[((size_t)bc * Idim + i) * Ndim + g];         // b2 = b1 + a1
        }
        // softmax over the 16 groups: xor masks {4,8,16,32} flip only g bits,
        // closure = 16 lanes (one per g, q fixed) -> z is the TRUE denominator
        float m = logit;
        m = fmaxf(m, __shfl_xor(m, 4));
        m = fmaxf(m, __shfl_xor(m, 8));
        m = fmaxf(m, __shfl_xor(m, 16));
        m = fmaxf(m, __shfl_xor(m, 32));
        float e = __expf(logit - m);
        float z = e;
        z += __shfl_xor(z, 4);
        z += __shfl_xor(z, 8);
        z += __shfl_xor(z, 16);
        z += __shfl_xor(z, 32);
        float c = e / z;

        #pragma unroll
        for (int j = 0; j < 8; ++j) sacc[j] = fmaf(c, u[j], sacc[j]);
    }

    // reduce the 4 waves' partial s over LDS, then one atomicAdd per element
    __shared__ float sl[4][512];
    #pragma unroll
    for (int j = 0; j < 8; ++j) sl[w][(l << 3) + j] = sacc[j];
    __syncthreads();
    for (int e2 = threadIdx.x; e2 < 512; e2 += 256) {
        float vsum = sl[0][e2] + sl[1][e2] + sl[2][e2] + sl[3][e2];
        atomicAdd(sout + (size_t)bglob * (Ndim * Ddim) + e2, vsum);
    }
}

// -------- squash: v = s*sq/((1+sq)*sqrt(sq)), sq = sum_d(s^2 + eps); 32 lanes per (b,n) row
__global__ __launch_bounds__(256) void squash_kernel(
    const float* __restrict__ s, float* __restrict__ vout, float scale, int bbase)
{
    const int tid = blockIdx.x * 256 + threadIdx.x;
    const int row = tid >> 5;               // chunk-local (b*N + n)
    const int d   = tid & 31;
    const size_t off = ((size_t)bbase * Ndim + row) * Ddim + d;
    float sv = s[off] * scale;
    float t = fmaf(sv, sv, EPSV);
    t += __shfl_xor(t, 1);
    t += __shfl_xor(t, 2);
    t += __shfl_xor(t, 4);
    t += __shfl_xor(t, 8);
    t += __shfl_xor(t, 16);                 // stays within 32-lane half
    float vv = sv * t / ((1.f + t) * sqrtf(t));
    vout[off] = vv;
}

extern "C" void kernel_launch(void* const* d_in, const int* in_sizes, int n_in,
                              void* d_out, int out_size, void* d_ws, size_t ws_size,
                              hipStream_t stream)
{
    (void)in_sizes; (void)n_in; (void)out_size;
    const float* x = (const float*)d_in[0];   // [B][I][K] fp32
    const float* W = (const float*)d_in[1];   // [N][I][D][K] fp32
    float* out = (float*)d_out;               // [B][N][D] fp32

    const size_t snd = (size_t)Bdim * Ndim * Ddim;        // 32768 floats
    const size_t fixed = 5 * snd * sizeof(float);         // s0,s1,s2,v0,v1

    // pick largest batch chunk that fits in workspace (u_hat bf16 + b-logits)
    int Bc = 64;
    while (Bc > 16) {
        size_t need = (size_t)Bc * Idim * Ndim * Ddim * 2 + (size_t)Bc * Idim * Ndim * 4 + fixed;
        if (need <= ws_size) break;
        Bc >>= 1;
    }

    char* p = (char*)d_ws;
    unsigned short* uhat = (unsigned short*)p; p += (size_t)Bc * Idim * Ndim * Ddim * 2;
    float* bbuf = (float*)p;                   p += (size_t)Bc * Idim * Ndim * 4;
    float* sbuf = (float*)p;
    float* s0 = sbuf;
    float* s1 = sbuf + snd;
    float* s2 = sbuf + 2 * snd;
    float* v0 = sbuf + 3 * snd;
    float* v1 = sbuf + 4 * snd;

    for (int bbase = 0; bbase < Bdim; bbase += Bc) {
        (void)hipMemsetAsync(sbuf, 0, 3 * snd * sizeof(float), stream);

        pass1_kernel<<<dim3(Ndim, Idim / 64), dim3(64 * (Bc / 16)), 0, stream>>>(
            W, x, uhat, s0, bbase);
        squash_kernel<<<dim3(Bc * 2), 256, 0, stream>>>(s0, v0, 1.f / 16.f, bbase);

        route_kernel<1><<<dim3(Bc, Idim / 128), 256, 0, stream>>>(uhat, v0, bbuf, s1, bbase);
        squash_kernel<<<dim3(Bc * 2), 256, 0, stream>>>(s1, v1, 1.f, bbase);

        route_kernel<0><<<dim3(Bc, Idim / 128), 256, 0, stream>>>(uhat, v1, bbuf, s2, bbase);
        squash_kernel<<<dim3(Bc * 2), 256, 0, stream>>>(s2, out, 1.f, bbase);
    }
}